// Round 7
// baseline (3404.038 us; speedup 1.0000x reference)
//
#include <hip/hip_runtime.h>
#include <hip/hip_bf16.h>

// R7: self-validating epoch-tagged exchange words (no flags, no drains).
//  - v element  = (epoch:32 | f32:32)   as one 8B relaxed agent atomic
//  - h elem-pair= (epoch:32 | 2xbf16:32) as one 8B relaxed agent atomic
//  Consumers poll the data words directly (tag == expected epoch, equality,
//  re-load only stale words). Removes per-exchange: producer vmcnt drain,
//  flag store, flag poll, separate data load (~3 MALL RTs per phase).
//  Dataflow is self-throttling: epoch t+2 producers can only run after all
//  t+1 consumers finished reading (their reads precede their publishes).
//  Prep resets v tags to -1 and h words to (0,ep=0) every launch -> immune
//  to 0xAA poisoning and cross-launch leftovers; equality check (not >=)
//  makes stale tags unambiguous.
#define T_STEPS 256
#define BATCH   128
#define DIN     512
#define DH      512
#define NGATE   2048
#define NCL     8
#define WPC     32
#define ROWS_CL 16
#define NWG     (NCL * WPC)

typedef __attribute__((ext_vector_type(8))) short short8;
typedef __attribute__((ext_vector_type(4))) float f32x4;
typedef unsigned long long u64;

#define OUT_HX ((size_t)T_STEPS * BATCH * DH)
#define OUT_CX (OUT_HX + (size_t)BATCH * DH)

// ---- ws layout ----
#define WB_OFF    0
#define XB_OFF    (4 * 1024 * 1024)
#define BT_OFF    (XB_OFF + 32 * 1024 * 1024)
#define CL_OFF    (BT_OFF + 8192)
#define CLV_OFF   0                        // v: 16*2048 u64 = 256 KB
#define CLH_OFF   (16 * 2048 * 8)          // h: 16*256  u64 =  32 KB
#define CL_STRIDE (320 * 1024)

#define LDS_W_BYTES 131072                 // 64 cols x 1024 K x bf16, swizzled
#define LDS_TOTAL   (LDS_W_BYTES + 4 * DH * 4)

__device__ inline ushort f2bf(float x) {
  uint u = __float_as_uint(x);
  u += 0x7fffu + ((u >> 16) & 1u);
  return (ushort)(u >> 16);
}
__device__ inline float sigm(float x) { return 1.f / (1.f + __expf(-x)); }
__device__ inline float tanhf_(float x) { return 1.f - 2.f / (1.f + __expf(2.f * x)); }

__device__ inline u64 ald64(const u64* p) {
  return __hip_atomic_load(p, __ATOMIC_RELAXED, __HIP_MEMORY_SCOPE_AGENT);
}
__device__ inline void ast64(u64* p, u64 v) {
  __hip_atomic_store(p, v, __ATOMIC_RELAXED, __HIP_MEMORY_SCOPE_AGENT);
}

// -------- prep kernels --------
__global__ void k_prep_w(const float* __restrict__ Wf, const float* __restrict__ Wi,
                         const float* __restrict__ Wu, const float* __restrict__ Wo,
                         ushort* __restrict__ Wb) {
  size_t i4 = ((size_t)blockIdx.x * 256 + threadIdx.x) * 4;
  if (i4 >= (size_t)NGATE * 1024) return;
  int row = (int)(i4 >> 10);
  int col = (int)(i4 & 1023);
  const float* W = (row < 512) ? Wf : (row < 1024) ? Wi : (row < 1536) ? Wu : Wo;
  int r = row & 511;
  float4 w = *(const float4*)&W[(size_t)r * 1024 + col];
  ushort4 o = make_ushort4(f2bf(w.x), f2bf(w.y), f2bf(w.z), f2bf(w.w));
  *(ushort4*)&Wb[i4] = o;
}

__global__ void k_prep_x(const float* __restrict__ X, ushort* __restrict__ Xb) {
  size_t i4 = ((size_t)blockIdx.x * 256 + threadIdx.x) * 4;
  if (i4 >= (size_t)T_STEPS * BATCH * DIN) return;
  float4 xv = *(const float4*)&X[i4];
  ushort4 o = make_ushort4(f2bf(xv.x), f2bf(xv.y), f2bf(xv.z), f2bf(xv.w));
  *(ushort4*)&Xb[i4] = o;
}

__global__ void k_prep_misc(const float* __restrict__ bf_, const float* __restrict__ tf_,
                            const float* __restrict__ bi_, const float* __restrict__ ti_,
                            const float* __restrict__ bu_, const float* __restrict__ tu_,
                            const float* __restrict__ bo_, const float* __restrict__ to_,
                            float* __restrict__ bt, char* __restrict__ clbase) {
  int idx = blockIdx.x * 256 + threadIdx.x;   // 0 .. 262143
  if (idx < NGATE) {
    int g = idx >> 9, k = idx & 511;
    const float* b = (g == 0) ? bf_ : (g == 1) ? bi_ : (g == 2) ? bu_ : bo_;
    const float* t = (g == 0) ? tf_ : (g == 1) ? ti_ : (g == 2) ? tu_ : to_;
    bt[idx] = b[k] + t[k];
  }
  if (idx < NCL * 16 * 256) {   // h words: (0 | ep=0) -> valid zeros for t=0
    int c = idx >> 12, w = idx & 4095;
    ((u64*)(clbase + (size_t)c * CL_STRIDE + CLH_OFF))[w] = 0ull;
  }
  if (idx < NCL * 16 * 2048) {  // v words: ep=-1 (never matches 1..256)
    int c = idx >> 15, w = idx & 32767;
    ((u64*)(clbase + (size_t)c * CL_STRIDE + CLV_OFF))[w] = 0xFFFFFFFF00000000ull;
  }
}

// -------- persistent main kernel --------
__global__ __launch_bounds__(256, 1) void qlstm_main(
    const ushort* __restrict__ Xb, const ushort* __restrict__ Wb,
    const float* __restrict__ bt, char* __restrict__ clbase,
    float* __restrict__ out) {
  extern __shared__ char smem[];
  ushort* wlds  = (ushort*)smem;                    // [64 cols][1024 K] swizzled
  float*  lds_g = (float*)(smem + LDS_W_BYTES);     // [4][512] gate exchange

  const int bid  = blockIdx.x;
  const int c    = bid & 7;
  const int mem  = bid >> 3;       // 0..31
  const int tid  = threadIdx.x;
  const int lane = tid & 63;
  const int wave = tid >> 6;

  char* cl     = clbase + (size_t)c * CL_STRIDE;
  u64*  v_pair = (u64*)(cl + CLV_OFF);   // [16 rows][2048 cols]
  u64*  h_pair = (u64*)(cl + CLH_OFF);   // [16 rows][256 words]

  const int nb    = mem * 64 + wave * 16;  // this wave's fused-gate col base
  const int ar    = lane & 15;
  const int kx    = (lane >> 4) << 3;      // 0,8,16,24 (ushort units)
  const int crow0 = c * ROWS_CL;
  const int row   = crow0 + mem;           // batch row (valid when mem<16)
  const int wrow  = wave * 16 + ar;        // local W col in LDS

  // ---- stage W slice into LDS (XOR-swizzled rows) ----
  {
    const char* wsrc = (const char*)(Wb + (size_t)(mem * 64) * 1024);
#pragma unroll
    for (int it = 0; it < 32; ++it) {
      int idx16 = it * 256 + tid;
      int r  = idx16 >> 7;
      int kb = (idx16 & 127) << 4;
      short8 w = *(const short8*)(wsrc + (size_t)r * 2048 + kb);
      *(short8*)((char*)wlds + (size_t)r * 2048 + (kb ^ ((r & 7) << 4))) = w;
    }
  }
#define WFRAG(KT) (*(const short8*)((const char*)wlds + (size_t)wrow * 2048 + \
                    ((((KT) * 64) + (kx << 1)) ^ ((ar & 7) << 4))))

  float btr[8];
  {
    const int e0 = lane << 3;
#pragma unroll
    for (int j = 0; j < 8; ++j) btr[j] = bt[wave * DH + e0 + j];
  }
  __syncthreads();

  float c0 = 0.f, c1 = 0.f;
  f32x4 accE = {0.f, 0.f, 0.f, 0.f}, accO = {0.f, 0.f, 0.f, 0.f};

#define XPART(TT) do {                                                        \
    accE = (f32x4){0.f, 0.f, 0.f, 0.f};                                       \
    accO = (f32x4){0.f, 0.f, 0.f, 0.f};                                       \
    const ushort* Ax = Xb + ((size_t)(TT) * BATCH + crow0 + ar) * DIN + kx;   \
    _Pragma("unroll")                                                         \
    for (int kt = 0; kt < 16; kt += 2) {                                      \
      short8 a0 = *(const short8*)(Ax + kt * 32);                             \
      short8 a1 = *(const short8*)(Ax + (kt + 1) * 32);                       \
      accE = __builtin_amdgcn_mfma_f32_16x16x32_bf16(a0, WFRAG(kt), accE, 0, 0, 0);     \
      accO = __builtin_amdgcn_mfma_f32_16x16x32_bf16(a1, WFRAG(kt + 1), accO, 0, 0, 0); \
    }                                                                         \
  } while (0)

  XPART(0);

  union FB { uint u[4]; short8 s8; };

  for (int t = 0; t < T_STEPS; ++t) {
    const uint epH = (uint)t;        // h tag consumed this step
    const uint epV = (uint)(t + 1);  // v/h tag produced this step

    // ---- h-part GEMM: self-validating h words, 2 halves of K ----
#pragma unroll
    for (int half = 0; half < 2; ++half) {
      u64 hw[32];
      const u64* hb = h_pair + (size_t)ar * 256 + half * 128 + (kx >> 1);
#pragma unroll
      for (int kt2 = 0; kt2 < 8; ++kt2)
#pragma unroll
        for (int j = 0; j < 4; ++j)
          hw[kt2 * 4 + j] = ald64(hb + kt2 * 16 + j);
      for (;;) {
        bool ok = true;
#pragma unroll
        for (int i = 0; i < 32; ++i) ok &= ((uint)(hw[i] >> 32) == epH);
        if (__all(ok)) break;
        __builtin_amdgcn_s_sleep(2);
#pragma unroll
        for (int kt2 = 0; kt2 < 8; ++kt2)
#pragma unroll
          for (int j = 0; j < 4; ++j)
            if ((uint)(hw[kt2 * 4 + j] >> 32) != epH)
              hw[kt2 * 4 + j] = ald64(hb + kt2 * 16 + j);
      }
#pragma unroll
      for (int kt2 = 0; kt2 < 8; kt2 += 2) {
        FB fe, fo;
#pragma unroll
        for (int j = 0; j < 4; ++j) {
          fe.u[j] = (uint)hw[kt2 * 4 + j];
          fo.u[j] = (uint)hw[(kt2 + 1) * 4 + j];
        }
        const int kt = 16 + half * 8 + kt2;
        accE = __builtin_amdgcn_mfma_f32_16x16x32_bf16(fe.s8, WFRAG(kt),     accE, 0, 0, 0);
        accO = __builtin_amdgcn_mfma_f32_16x16x32_bf16(fo.s8, WFRAG(kt + 1), accO, 0, 0, 0);
      }
    }

    // ---- v publish: (epV | f32), no drain, no flag ----
    {
      const int rbase = (lane >> 4) << 2;
      u64* vp = v_pair + (size_t)rbase * 2048 + nb + ar;
#pragma unroll
      for (int r = 0; r < 4; ++r) {
        u64 w = ((u64)epV << 32) | (u64)__float_as_uint(accE[r] + accO[r]);
        ast64(&vp[(size_t)r * 2048], w);
      }
    }

    // ---- overlapped x-part of t+1 (needs no h) ----
    if (t + 1 < T_STEPS) XPART(t + 1);

    if (mem < ROWS_CL) {
      // ---- scan row `mem`: wave = gate; poll v words directly ----
      const int g = wave;
      u64 vw[8];
      const u64* vr = v_pair + (size_t)mem * 2048 + g * 512 + lane * 8;
#pragma unroll
      for (int j = 0; j < 8; ++j) vw[j] = ald64(vr + j);
      for (;;) {
        bool ok = true;
#pragma unroll
        for (int j = 0; j < 8; ++j) ok &= ((uint)(vw[j] >> 32) == epV);
        if (__all(ok)) break;
        __builtin_amdgcn_s_sleep(2);
#pragma unroll
        for (int j = 0; j < 8; ++j)
          if ((uint)(vw[j] >> 32) != epV) vw[j] = ald64(vr + j);
      }
      {
        float p0 = __cosf(__uint_as_float((uint)vw[0]) + btr[0]);
        float p1 = __cosf(__uint_as_float((uint)vw[1]) + btr[1]);
        float p2 = __cosf(__uint_as_float((uint)vw[2]) + btr[2]);
        float p3 = __cosf(__uint_as_float((uint)vw[3]) + btr[3]);
        float p4 = __cosf(__uint_as_float((uint)vw[4]) + btr[4]);
        float p5 = __cosf(__uint_as_float((uint)vw[5]) + btr[5]);
        float p6 = __cosf(__uint_as_float((uint)vw[6]) + btr[6]);
        float p7 = __cosf(__uint_as_float((uint)vw[7]) + btr[7]);
        float q0 = p0, q1 = q0 * p1, q2 = q1 * p2, q3 = q2 * p3;
        float q4 = q3 * p4, q5 = q4 * p5, q6 = q5 * p6, q7 = q6 * p7;
        float a = q7;
#pragma unroll
        for (int off = 1; off < 64; off <<= 1) {
          float o = __shfl_up(a, off);
          a = (lane >= off) ? a * o : a;
        }
        float ex = __shfl_up(a, 1);
        ex = (lane == 0) ? 1.f : ex;
        float G0 = ex * q0, G1 = ex * q1, G2 = ex * q2, G3 = ex * q3;
        float G4 = ex * q4, G5 = ex * q5, G6 = ex * q6, G7 = ex * q7;
        float4 r0, r1;
        if (g == 2) {
          r0 = make_float4(tanhf_(G0), tanhf_(G1), tanhf_(G2), tanhf_(G3));
          r1 = make_float4(tanhf_(G4), tanhf_(G5), tanhf_(G6), tanhf_(G7));
        } else {
          r0 = make_float4(sigm(G0), sigm(G1), sigm(G2), sigm(G3));
          r1 = make_float4(sigm(G4), sigm(G5), sigm(G6), sigm(G7));
        }
        const int e0 = lane << 3;
        *(float4*)&lds_g[g * DH + e0]     = r0;
        *(float4*)&lds_g[g * DH + e0 + 4] = r1;
      }
      __syncthreads();
      {
        const int k = tid << 1;
        float f0 = lds_g[0 * DH + k], f1 = lds_g[0 * DH + k + 1];
        float i0 = lds_g[1 * DH + k], i1 = lds_g[1 * DH + k + 1];
        float u0 = lds_g[2 * DH + k], u1 = lds_g[2 * DH + k + 1];
        float o0 = lds_g[3 * DH + k], o1 = lds_g[3 * DH + k + 1];
        c0 = f0 * c0 + i0 * u0;
        c1 = f1 * c1 + i1 * u1;
        float h0 = o0 * tanhf_(c0);
        float h1 = o1 * tanhf_(c1);
        float2 hp = make_float2(h0, h1);
        *(float2*)&out[((size_t)t * BATCH + row) * DH + k] = hp;
        uint pack = ((uint)f2bf(h1) << 16) | (uint)f2bf(h0);
        ast64(&h_pair[(size_t)mem * 256 + tid], ((u64)epV << 32) | (u64)pack);
        if (t == T_STEPS - 1) {
          *(float2*)&out[OUT_HX + (size_t)row * DH + k] = hp;
          float2 cp = make_float2(c0, c1);
          *(float2*)&out[OUT_CX + (size_t)row * DH + k] = cp;
        }
      }
      __syncthreads();   // protect lds_g against next-iteration overwrite
    }
  }
#undef XPART
#undef WFRAG
}

extern "C" void kernel_launch(void* const* d_in, const int* in_sizes, int n_in,
                              void* d_out, int out_size, void* d_ws, size_t ws_size,
                              hipStream_t stream) {
  const float* X  = (const float*)d_in[0];
  const float* Wf = (const float*)d_in[1];
  const float* bf = (const float*)d_in[2];
  const float* tf = (const float*)d_in[3];
  const float* Wi = (const float*)d_in[4];
  const float* bi = (const float*)d_in[5];
  const float* ti = (const float*)d_in[6];
  const float* Wu = (const float*)d_in[7];
  const float* bu = (const float*)d_in[8];
  const float* tu = (const float*)d_in[9];
  const float* Wo = (const float*)d_in[10];
  const float* bo = (const float*)d_in[11];
  const float* to = (const float*)d_in[12];

  char* ws = (char*)d_ws;
  ushort* Wb     = (ushort*)(ws + WB_OFF);
  ushort* Xb     = (ushort*)(ws + XB_OFF);
  float*  bt     = (float*)(ws + BT_OFF);
  char*   clbase = ws + CL_OFF;
  float*  out    = (float*)d_out;

  static bool attr_set = false;
  if (!attr_set) {
    hipFuncSetAttribute((const void*)qlstm_main,
                        hipFuncAttributeMaxDynamicSharedMemorySize, LDS_TOTAL);
    attr_set = true;
  }

  k_prep_w<<<dim3((NGATE * 1024 / 4 + 255) / 256), dim3(256), 0, stream>>>(Wf, Wi, Wu, Wo, Wb);
  k_prep_x<<<dim3((T_STEPS * BATCH * DIN / 4 + 255) / 256), dim3(256), 0, stream>>>(X, Xb);
  k_prep_misc<<<dim3(1024), dim3(256), 0, stream>>>(bf, tf, bi, ti, bu, tu, bo, to, bt, clbase);
  qlstm_main<<<dim3(NWG), dim3(256), LDS_TOTAL, stream>>>(Xb, Wb, bt, clbase, out);
}

// Round 8
// 2448.339 us; speedup vs baseline: 1.3903x; 1.3903x over previous
//
#include <hip/hip_runtime.h>
#include <hip/hip_bf16.h>

// R8: R6 transport (relaxed agent-scope flags + bulk data) with fine-grained
// sync structure:
//  - per-WAVE arrive: each wave drains its own stores (vmcnt(0)) and writes
//    its own padded flag slot -> no __syncthreads funnel, no tid0 serializer.
//  - gate-local fan-in: scan wave g polls only the 32 producer-wave slots
//    covering gate g's 512 cols; each lane polls the slot for ITS 8 cols.
//  - busy-poll (no s_sleep): detect latency ~1 MALL RT.
//  - trailing lds_g syncthreads dropped (WAR ordered via slotB->slotA chain).
//  - XPART(t+1) before the scan block: hidden for scan WGs too.
#define T_STEPS 256
#define BATCH   128
#define DIN     512
#define DH      512
#define NGATE   2048
#define NCL     8
#define WPC     32
#define ROWS_CL 16
#define NWG     (NCL * WPC)

typedef __attribute__((ext_vector_type(8))) short short8;
typedef __attribute__((ext_vector_type(4))) float f32x4;
typedef unsigned long long u64;

#define OUT_HX ((size_t)T_STEPS * BATCH * DH)
#define OUT_CX (OUT_HX + (size_t)BATCH * DH)

// ---- ws layout ----
#define WB_OFF    0
#define XB_OFF    (4 * 1024 * 1024)
#define BT_OFF    (XB_OFF + 32 * 1024 * 1024)
#define CL_OFF    (BT_OFF + 8192)
#define CL_STRIDE (192 * 1024)
#define CLV_OFF   0                    // v: 16*2048*4 = 131072 B
#define CLH_OFF   131072               // h: 16*256 u32 = 16384 B
#define CLFA_OFF  147456               // slotA: 128 slots x 128 B = 16384 B
#define CLFB_OFF  (CLFA_OFF + 16384)   // slotB: 64 slots x 128 B = 8192 B
#define SLOT_STRIDE 32                 // ints per slot (128 B)

#define LDS_W_BYTES 131072             // 64 cols x 1024 K x bf16, swizzled
#define LDS_TOTAL   (LDS_W_BYTES + 4 * DH * 4)

__device__ inline ushort f2bf(float x) {
  uint u = __float_as_uint(x);
  u += 0x7fffu + ((u >> 16) & 1u);
  return (ushort)(u >> 16);
}
__device__ inline float sigm(float x) { return 1.f / (1.f + __expf(-x)); }
__device__ inline float tanhf_(float x) { return 1.f - 2.f / (1.f + __expf(2.f * x)); }

__device__ inline u64 ald64(const u64* p) {
  return __hip_atomic_load(p, __ATOMIC_RELAXED, __HIP_MEMORY_SCOPE_AGENT);
}
__device__ inline void ast32(uint* p, uint v) {
  __hip_atomic_store(p, v, __ATOMIC_RELAXED, __HIP_MEMORY_SCOPE_AGENT);
}
__device__ inline int aldi(const int* p) {
  return __hip_atomic_load(p, __ATOMIC_RELAXED, __HIP_MEMORY_SCOPE_AGENT);
}
__device__ inline void asti(int* p, int v) {
  __hip_atomic_store(p, v, __ATOMIC_RELAXED, __HIP_MEMORY_SCOPE_AGENT);
}
__device__ inline void waitvm() { asm volatile("s_waitcnt vmcnt(0)" ::: "memory"); }

union U16 { u64 q[2]; short8 s; };
union UF2 { u64 q; float f[2]; };

// -------- prep kernels --------
__global__ void k_prep_w(const float* __restrict__ Wf, const float* __restrict__ Wi,
                         const float* __restrict__ Wu, const float* __restrict__ Wo,
                         ushort* __restrict__ Wb) {
  size_t i4 = ((size_t)blockIdx.x * 256 + threadIdx.x) * 4;
  if (i4 >= (size_t)NGATE * 1024) return;
  int row = (int)(i4 >> 10);
  int col = (int)(i4 & 1023);
  const float* W = (row < 512) ? Wf : (row < 1024) ? Wi : (row < 1536) ? Wu : Wo;
  int r = row & 511;
  float4 w = *(const float4*)&W[(size_t)r * 1024 + col];
  ushort4 o = make_ushort4(f2bf(w.x), f2bf(w.y), f2bf(w.z), f2bf(w.w));
  *(ushort4*)&Wb[i4] = o;
}

__global__ void k_prep_x(const float* __restrict__ X, ushort* __restrict__ Xb) {
  size_t i4 = ((size_t)blockIdx.x * 256 + threadIdx.x) * 4;
  if (i4 >= (size_t)T_STEPS * BATCH * DIN) return;
  float4 xv = *(const float4*)&X[i4];
  ushort4 o = make_ushort4(f2bf(xv.x), f2bf(xv.y), f2bf(xv.z), f2bf(xv.w));
  *(ushort4*)&Xb[i4] = o;
}

__global__ void k_prep_misc(const float* __restrict__ bf_, const float* __restrict__ tf_,
                            const float* __restrict__ bi_, const float* __restrict__ ti_,
                            const float* __restrict__ bu_, const float* __restrict__ tu_,
                            const float* __restrict__ bo_, const float* __restrict__ to_,
                            float* __restrict__ bt, char* __restrict__ clbase) {
  int idx = blockIdx.x * 256 + threadIdx.x;
  if (idx < NGATE) {
    int g = idx >> 9, k = idx & 511;
    const float* b = (g == 0) ? bf_ : (g == 1) ? bi_ : (g == 2) ? bu_ : bo_;
    const float* t = (g == 0) ? tf_ : (g == 1) ? ti_ : (g == 2) ? tu_ : to_;
    bt[idx] = b[k] + t[k];
  }
  if (idx < NCL * 4096) {  // zero h (16*256 u32 words per cluster)
    int c = idx >> 12, w = idx & 4095;
    ((uint*)(clbase + (size_t)c * CL_STRIDE + CLH_OFF))[w] = 0u;
  }
  if (idx < NCL * 6144) {  // zero flag region (24 KB per cluster)
    int c = idx / 6144, w = idx % 6144;
    ((int*)(clbase + (size_t)c * CL_STRIDE + CLFA_OFF))[w] = 0;
  }
}

// -------- persistent main kernel --------
__global__ __launch_bounds__(256, 1) void qlstm_main(
    const ushort* __restrict__ Xb, const ushort* __restrict__ Wb,
    const float* __restrict__ bt, char* __restrict__ clbase,
    float* __restrict__ out) {
  extern __shared__ char smem[];
  ushort* wlds  = (ushort*)smem;                    // [64 cols][1024 K] swizzled
  float*  lds_g = (float*)(smem + LDS_W_BYTES);     // [4][512] gate exchange

  const int bid  = blockIdx.x;
  const int c    = bid & 7;
  const int mem  = bid >> 3;       // 0..31
  const int tid  = threadIdx.x;
  const int lane = tid & 63;
  const int wave = tid >> 6;

  char*   cl    = clbase + (size_t)c * CL_STRIDE;
  float*  v_cl  = (float*)(cl + CLV_OFF);
  u64*    h_cl  = (u64*)(cl + CLH_OFF);
  uint*   h_cl32= (uint*)(cl + CLH_OFF);
  int*    slotA = (int*)(cl + CLFA_OFF);   // [128] waves, 128B stride
  int*    slotB = (int*)(cl + CLFB_OFF);   // [64] waves, 128B stride

  const int nb    = mem * 64 + wave * 16;  // this wave's fused-gate col base
  const int ar    = lane & 15;
  const int kx    = (lane >> 4) << 3;      // 0,8,16,24 (ushort units)
  const int crow0 = c * ROWS_CL;
  const int row   = crow0 + mem;           // batch row (valid when mem<16)
  const int wrow  = wave * 16 + ar;        // local W col in LDS

  // ---- stage W slice into LDS (XOR-swizzled rows) ----
  {
    const char* wsrc = (const char*)(Wb + (size_t)(mem * 64) * 1024);
#pragma unroll
    for (int it = 0; it < 32; ++it) {
      int idx16 = it * 256 + tid;
      int r  = idx16 >> 7;
      int kb = (idx16 & 127) << 4;
      short8 w = *(const short8*)(wsrc + (size_t)r * 2048 + kb);
      *(short8*)((char*)wlds + (size_t)r * 2048 + (kb ^ ((r & 7) << 4))) = w;
    }
  }
#define WFRAG(KT) (*(const short8*)((const char*)wlds + (size_t)wrow * 2048 + \
                    ((((KT) * 64) + (kx << 1)) ^ ((ar & 7) << 4))))

  float btr[8];
  {
    const int e0 = lane << 3;
#pragma unroll
    for (int j = 0; j < 8; ++j) btr[j] = bt[wave * DH + e0 + j];
  }
  __syncthreads();

  // poll-slot pointers (per-lane, precomputed)
  // scan wave g, lane l covers gate-cols [8l,8l+8) -> producer (8g + (l>>3)),
  // producer wave (l&7)>>1 -> slot 32g + ((l>>3)<<2) + ((l&7)>>1)
  const int* pollA = &slotA[(32 * wave + ((lane >> 3) << 2) + ((lane & 7) >> 1)) * SLOT_STRIDE];
  const int* pollB = &slotB[lane * SLOT_STRIDE];     // 64 slots: 16 rows x 4 waves
  int* arrA = &slotA[(mem * 4 + wave) * SLOT_STRIDE];
  int* arrB = &slotB[(mem * 4 + wave) * SLOT_STRIDE];

  float c0 = 0.f, c1 = 0.f;
  f32x4 accE = {0.f, 0.f, 0.f, 0.f}, accO = {0.f, 0.f, 0.f, 0.f};

#define XPART(TT) do {                                                        \
    accE = (f32x4){0.f, 0.f, 0.f, 0.f};                                       \
    accO = (f32x4){0.f, 0.f, 0.f, 0.f};                                       \
    const ushort* Ax = Xb + ((size_t)(TT) * BATCH + crow0 + ar) * DIN + kx;   \
    _Pragma("unroll")                                                         \
    for (int kt = 0; kt < 16; kt += 2) {                                      \
      short8 a0 = *(const short8*)(Ax + kt * 32);                             \
      short8 a1 = *(const short8*)(Ax + (kt + 1) * 32);                       \
      accE = __builtin_amdgcn_mfma_f32_16x16x32_bf16(a0, WFRAG(kt), accE, 0, 0, 0);     \
      accO = __builtin_amdgcn_mfma_f32_16x16x32_bf16(a1, WFRAG(kt + 1), accO, 0, 0, 0); \
    }                                                                         \
  } while (0)

  XPART(0);

  for (int t = 0; t < T_STEPS; ++t) {
    const int ep = t + 1;

    // ---- wait h(t): all 16 rows x 4 producer-waves (t=0: init 0 passes) ----
    {
      for (;;) {
        int s = aldi(pollB);
        if (__all(s >= t)) break;
      }
      asm volatile("" ::: "memory");
    }

    // ---- h-part GEMM: A = h (coherence-point loads), B = LDS W frags ----
    {
      U16 af[16];
#pragma unroll
      for (int kt = 0; kt < 16; ++kt) {
        const u64* p = h_cl + (((size_t)ar * DH + kt * 32 + kx) >> 2);
        af[kt].q[0] = ald64(p);
        af[kt].q[1] = ald64(p + 1);
      }
#pragma unroll
      for (int kt = 0; kt < 16; kt += 2) {
        accE = __builtin_amdgcn_mfma_f32_16x16x32_bf16(af[kt].s,     WFRAG(16 + kt),     accE, 0, 0, 0);
        accO = __builtin_amdgcn_mfma_f32_16x16x32_bf16(af[kt + 1].s, WFRAG(16 + kt + 1), accO, 0, 0, 0);
      }
    }
    // ---- v publish (per-wave): stores -> own vmcnt drain -> own slot ----
    {
      const int rbase = (lane >> 4) << 2;
      float* vp = v_cl + (size_t)rbase * NGATE + nb + ar;
#pragma unroll
      for (int r = 0; r < 4; ++r)
        ast32((uint*)&vp[(size_t)r * NGATE], __float_as_uint(accE[r] + accO[r]));
      waitvm();
      if (lane == 0) asti(arrA, ep);
    }

    // ---- overlapped x-part of t+1 (hidden under v-hop latency) ----
    if (t + 1 < T_STEPS) XPART(t + 1);

    if (mem < ROWS_CL) {
      // ---- scan row `mem`: wave g polls only gate-g producer waves ----
      const int g = wave;
      {
        for (;;) {
          int s = aldi(pollA);
          if (__all(s >= ep)) break;
        }
        asm volatile("" ::: "memory");
      }
      {
        const int e0 = lane << 3;
        const u64* vr = (const u64*)(v_cl + (size_t)mem * NGATE + g * DH + e0);
        UF2 w0, w1, w2, w3;
        w0.q = ald64(vr);     w1.q = ald64(vr + 1);
        w2.q = ald64(vr + 2); w3.q = ald64(vr + 3);
        float p0 = __cosf(w0.f[0] + btr[0]);
        float p1 = __cosf(w0.f[1] + btr[1]);
        float p2 = __cosf(w1.f[0] + btr[2]);
        float p3 = __cosf(w1.f[1] + btr[3]);
        float p4 = __cosf(w2.f[0] + btr[4]);
        float p5 = __cosf(w2.f[1] + btr[5]);
        float p6 = __cosf(w3.f[0] + btr[6]);
        float p7 = __cosf(w3.f[1] + btr[7]);
        float q0 = p0, q1 = q0 * p1, q2 = q1 * p2, q3 = q2 * p3;
        float q4 = q3 * p4, q5 = q4 * p5, q6 = q5 * p6, q7 = q6 * p7;
        float a = q7;
#pragma unroll
        for (int off = 1; off < 64; off <<= 1) {
          float o = __shfl_up(a, off);
          a = (lane >= off) ? a * o : a;
        }
        float ex = __shfl_up(a, 1);
        ex = (lane == 0) ? 1.f : ex;
        float G0 = ex * q0, G1 = ex * q1, G2 = ex * q2, G3 = ex * q3;
        float G4 = ex * q4, G5 = ex * q5, G6 = ex * q6, G7 = ex * q7;
        float4 r0, r1;
        if (g == 2) {
          r0 = make_float4(tanhf_(G0), tanhf_(G1), tanhf_(G2), tanhf_(G3));
          r1 = make_float4(tanhf_(G4), tanhf_(G5), tanhf_(G6), tanhf_(G7));
        } else {
          r0 = make_float4(sigm(G0), sigm(G1), sigm(G2), sigm(G3));
          r1 = make_float4(sigm(G4), sigm(G5), sigm(G6), sigm(G7));
        }
        *(float4*)&lds_g[g * DH + e0]     = r0;
        *(float4*)&lds_g[g * DH + e0 + 4] = r1;
      }
      __syncthreads();   // all 4 gate slices in lds_g
      {
        const int k = tid << 1;
        float f0 = lds_g[0 * DH + k], f1 = lds_g[0 * DH + k + 1];
        float i0 = lds_g[1 * DH + k], i1 = lds_g[1 * DH + k + 1];
        float u0 = lds_g[2 * DH + k], u1 = lds_g[2 * DH + k + 1];
        float o0 = lds_g[3 * DH + k], o1 = lds_g[3 * DH + k + 1];
        c0 = f0 * c0 + i0 * u0;
        c1 = f1 * c1 + i1 * u1;
        float h0 = o0 * tanhf_(c0);
        float h1 = o1 * tanhf_(c1);
        float2 hp = make_float2(h0, h1);
        *(float2*)&out[((size_t)t * BATCH + row) * DH + k] = hp;
        uint hbits = ((uint)f2bf(h1) << 16) | (uint)f2bf(h0);
        ast32(&h_cl32[mem * 256 + tid], hbits);
        if (t == T_STEPS - 1) {
          *(float2*)&out[OUT_HX + (size_t)row * DH + k] = hp;
          float2 cp = make_float2(c0, c1);
          *(float2*)&out[OUT_CX + (size_t)row * DH + k] = cp;
        }
        // per-wave h arrive: own stores drained, own slot
        waitvm();
        if (lane == 0) asti(arrB, ep);
      }
      // no trailing __syncthreads: lds_g WAR is ordered via
      // slotB(ep) -> producers' v(ep+1) -> slotA(ep+1) -> next lds_g write.
    }
  }
#undef XPART
#undef WFRAG
}

extern "C" void kernel_launch(void* const* d_in, const int* in_sizes, int n_in,
                              void* d_out, int out_size, void* d_ws, size_t ws_size,
                              hipStream_t stream) {
  const float* X  = (const float*)d_in[0];
  const float* Wf = (const float*)d_in[1];
  const float* bf = (const float*)d_in[2];
  const float* tf = (const float*)d_in[3];
  const float* Wi = (const float*)d_in[4];
  const float* bi = (const float*)d_in[5];
  const float* ti = (const float*)d_in[6];
  const float* Wu = (const float*)d_in[7];
  const float* bu = (const float*)d_in[8];
  const float* tu = (const float*)d_in[9];
  const float* Wo = (const float*)d_in[10];
  const float* bo = (const float*)d_in[11];
  const float* to = (const float*)d_in[12];

  char* ws = (char*)d_ws;
  ushort* Wb     = (ushort*)(ws + WB_OFF);
  ushort* Xb     = (ushort*)(ws + XB_OFF);
  float*  bt     = (float*)(ws + BT_OFF);
  char*   clbase = ws + CL_OFF;
  float*  out    = (float*)d_out;

  static bool attr_set = false;
  if (!attr_set) {
    hipFuncSetAttribute((const void*)qlstm_main,
                        hipFuncAttributeMaxDynamicSharedMemorySize, LDS_TOTAL);
    attr_set = true;
  }

  k_prep_w<<<dim3((NGATE * 1024 / 4 + 255) / 256), dim3(256), 0, stream>>>(Wf, Wi, Wu, Wo, Wb);
  k_prep_x<<<dim3((T_STEPS * BATCH * DIN / 4 + 255) / 256), dim3(256), 0, stream>>>(X, Xb);
  k_prep_misc<<<dim3(256), dim3(256), 0, stream>>>(bf, tf, bi, ti, bu, tu, bo, to, bt, clbase);
  qlstm_main<<<dim3(NWG), dim3(256), LDS_TOTAL, stream>>>(Xb, Wb, bt, clbase, out);
}

// Round 9
// 2286.247 us; speedup vs baseline: 1.4889x; 1.0709x over previous
//
#include <hip/hip_runtime.h>
#include <hip/hip_bf16.h>

// R9 = R6 with the two arrive funnels removed (everything else identical):
//  - arrive = per-WAVE: each wave drains ITS OWN stores (vmcnt(0)), lane0
//    writes its own 128B-padded sentinel slot. No __syncthreads funnel, no
//    tid0 single-writer. slotA: 128 slots (32 WG x 4 waves); slotB: 64.
//  - polls stay R6-narrow: one wave0 per WG polls, lane-parallel slots,
//    s_sleep backoff (sleep(4) for the long-window h-poll, sleep(1) for the
//    short-window v-poll), then __syncthreads broadcast + one-shot bulk load.
//  - scan publishes h words BEFORE out[] stores: sentinel drain no longer
//    waits on d_out HBM writes.
//  - XPART placement unchanged from R6 (R8 showed moving it earlier hurts).
#define T_STEPS 256
#define BATCH   128
#define DIN     512
#define DH      512
#define NGATE   2048
#define NCL     8
#define WPC     32
#define ROWS_CL 16
#define NWG     (NCL * WPC)

typedef __attribute__((ext_vector_type(8))) short short8;
typedef __attribute__((ext_vector_type(4))) float f32x4;
typedef unsigned long long u64;

#define OUT_HX ((size_t)T_STEPS * BATCH * DH)
#define OUT_CX (OUT_HX + (size_t)BATCH * DH)

// ---- ws layout ----
#define WB_OFF    0
#define XB_OFF    (4 * 1024 * 1024)
#define BT_OFF    (XB_OFF + 32 * 1024 * 1024)
#define CL_OFF    (BT_OFF + 8192)
#define CL_STRIDE (192 * 1024)
#define CLV_OFF   0                    // v: 16*2048*4 = 131072 B
#define CLH_OFF   131072               // h: 16*256 u32 = 16384 B
#define CLFA_OFF  147456               // slotA: 128 slots x 128 B = 16384 B
#define CLFB_OFF  (CLFA_OFF + 16384)   // slotB: 64 slots x 128 B = 8192 B
#define SLOT_STRIDE 32                 // ints per slot (128 B)

#define LDS_W_BYTES 131072             // 64 cols x 1024 K x bf16, swizzled
#define LDS_TOTAL   (LDS_W_BYTES + 4 * DH * 4)

__device__ inline ushort f2bf(float x) {
  uint u = __float_as_uint(x);
  u += 0x7fffu + ((u >> 16) & 1u);
  return (ushort)(u >> 16);
}
__device__ inline float sigm(float x) { return 1.f / (1.f + __expf(-x)); }
__device__ inline float tanhf_(float x) { return 1.f - 2.f / (1.f + __expf(2.f * x)); }

__device__ inline u64 ald64(const u64* p) {
  return __hip_atomic_load(p, __ATOMIC_RELAXED, __HIP_MEMORY_SCOPE_AGENT);
}
__device__ inline void ast32(uint* p, uint v) {
  __hip_atomic_store(p, v, __ATOMIC_RELAXED, __HIP_MEMORY_SCOPE_AGENT);
}
__device__ inline int aldi(const int* p) {
  return __hip_atomic_load(p, __ATOMIC_RELAXED, __HIP_MEMORY_SCOPE_AGENT);
}
__device__ inline void asti(int* p, int v) {
  __hip_atomic_store(p, v, __ATOMIC_RELAXED, __HIP_MEMORY_SCOPE_AGENT);
}
__device__ inline void waitvm() { asm volatile("s_waitcnt vmcnt(0)" ::: "memory"); }

union U16 { u64 q[2]; short8 s; };
union UF2 { u64 q; float f[2]; };

// -------- prep kernels --------
__global__ void k_prep_w(const float* __restrict__ Wf, const float* __restrict__ Wi,
                         const float* __restrict__ Wu, const float* __restrict__ Wo,
                         ushort* __restrict__ Wb) {
  size_t i4 = ((size_t)blockIdx.x * 256 + threadIdx.x) * 4;
  if (i4 >= (size_t)NGATE * 1024) return;
  int row = (int)(i4 >> 10);
  int col = (int)(i4 & 1023);
  const float* W = (row < 512) ? Wf : (row < 1024) ? Wi : (row < 1536) ? Wu : Wo;
  int r = row & 511;
  float4 w = *(const float4*)&W[(size_t)r * 1024 + col];
  ushort4 o = make_ushort4(f2bf(w.x), f2bf(w.y), f2bf(w.z), f2bf(w.w));
  *(ushort4*)&Wb[i4] = o;
}

__global__ void k_prep_x(const float* __restrict__ X, ushort* __restrict__ Xb) {
  size_t i4 = ((size_t)blockIdx.x * 256 + threadIdx.x) * 4;
  if (i4 >= (size_t)T_STEPS * BATCH * DIN) return;
  float4 xv = *(const float4*)&X[i4];
  ushort4 o = make_ushort4(f2bf(xv.x), f2bf(xv.y), f2bf(xv.z), f2bf(xv.w));
  *(ushort4*)&Xb[i4] = o;
}

__global__ void k_prep_misc(const float* __restrict__ bf_, const float* __restrict__ tf_,
                            const float* __restrict__ bi_, const float* __restrict__ ti_,
                            const float* __restrict__ bu_, const float* __restrict__ tu_,
                            const float* __restrict__ bo_, const float* __restrict__ to_,
                            float* __restrict__ bt, char* __restrict__ clbase) {
  int idx = blockIdx.x * 256 + threadIdx.x;
  if (idx < NGATE) {
    int g = idx >> 9, k = idx & 511;
    const float* b = (g == 0) ? bf_ : (g == 1) ? bi_ : (g == 2) ? bu_ : bo_;
    const float* t = (g == 0) ? tf_ : (g == 1) ? ti_ : (g == 2) ? tu_ : to_;
    bt[idx] = b[k] + t[k];
  }
  if (idx < NCL * 4096) {  // zero h (16*256 u32 words per cluster)
    int c = idx >> 12, w = idx & 4095;
    ((uint*)(clbase + (size_t)c * CL_STRIDE + CLH_OFF))[w] = 0u;
  }
  if (idx < NCL * 6144) {  // zero flag region (24 KB per cluster)
    int c = idx / 6144, w = idx % 6144;
    ((int*)(clbase + (size_t)c * CL_STRIDE + CLFA_OFF))[w] = 0;
  }
}

// -------- persistent main kernel --------
__global__ __launch_bounds__(256, 1) void qlstm_main(
    const ushort* __restrict__ Xb, const ushort* __restrict__ Wb,
    const float* __restrict__ bt, char* __restrict__ clbase,
    float* __restrict__ out) {
  extern __shared__ char smem[];
  ushort* wlds  = (ushort*)smem;                    // [64 cols][1024 K] swizzled
  float*  lds_g = (float*)(smem + LDS_W_BYTES);     // [4][512] gate exchange

  const int bid  = blockIdx.x;
  const int c    = bid & 7;
  const int mem  = bid >> 3;       // 0..31
  const int tid  = threadIdx.x;
  const int lane = tid & 63;
  const int wave = tid >> 6;

  char*   cl    = clbase + (size_t)c * CL_STRIDE;
  float*  v_cl  = (float*)(cl + CLV_OFF);
  u64*    h_cl  = (u64*)(cl + CLH_OFF);
  uint*   h_cl32= (uint*)(cl + CLH_OFF);
  int*    slotA = (int*)(cl + CLFA_OFF);   // [128] producer waves
  int*    slotB = (int*)(cl + CLFB_OFF);   // [64]  scan waves

  const int nb    = mem * 64 + wave * 16;  // this wave's fused-gate col base
  const int ar    = lane & 15;
  const int kx    = (lane >> 4) << 3;      // 0,8,16,24 (ushort units)
  const int crow0 = c * ROWS_CL;
  const int row   = crow0 + mem;           // batch row (valid when mem<16)
  const int wrow  = wave * 16 + ar;        // local W col in LDS

  // ---- stage W slice into LDS (XOR-swizzled rows) ----
  {
    const char* wsrc = (const char*)(Wb + (size_t)(mem * 64) * 1024);
#pragma unroll
    for (int it = 0; it < 32; ++it) {
      int idx16 = it * 256 + tid;
      int r  = idx16 >> 7;
      int kb = (idx16 & 127) << 4;
      short8 w = *(const short8*)(wsrc + (size_t)r * 2048 + kb);
      *(short8*)((char*)wlds + (size_t)r * 2048 + (kb ^ ((r & 7) << 4))) = w;
    }
  }
#define WFRAG(KT) (*(const short8*)((const char*)wlds + (size_t)wrow * 2048 + \
                    ((((KT) * 64) + (kx << 1)) ^ ((ar & 7) << 4))))

  float btr[8];
  {
    const int e0 = lane << 3;
#pragma unroll
    for (int j = 0; j < 8; ++j) btr[j] = bt[wave * DH + e0 + j];
  }
  __syncthreads();

  int* arrA = &slotA[(mem * 4 + wave) * SLOT_STRIDE];
  int* arrB = &slotB[(mem * 4 + wave) * SLOT_STRIDE];  // valid when mem<16

  float c0 = 0.f, c1 = 0.f;
  f32x4 accE = {0.f, 0.f, 0.f, 0.f}, accO = {0.f, 0.f, 0.f, 0.f};

#define XPART(TT) do {                                                        \
    accE = (f32x4){0.f, 0.f, 0.f, 0.f};                                       \
    accO = (f32x4){0.f, 0.f, 0.f, 0.f};                                       \
    const ushort* Ax = Xb + ((size_t)(TT) * BATCH + crow0 + ar) * DIN + kx;   \
    _Pragma("unroll")                                                         \
    for (int kt = 0; kt < 16; kt += 2) {                                      \
      short8 a0 = *(const short8*)(Ax + kt * 32);                             \
      short8 a1 = *(const short8*)(Ax + (kt + 1) * 32);                       \
      accE = __builtin_amdgcn_mfma_f32_16x16x32_bf16(a0, WFRAG(kt), accE, 0, 0, 0);     \
      accO = __builtin_amdgcn_mfma_f32_16x16x32_bf16(a1, WFRAG(kt + 1), accO, 0, 0, 0); \
    }                                                                         \
  } while (0)

  XPART(0);

  for (int t = 0; t < T_STEPS; ++t) {
    const int ep = t + 1;

    // ---- wait h(t): 64 scan-wave sentinels (t=0: prep-zeroed slots pass) ----
    if (wave == 0) {
      const int* my = &slotB[lane * SLOT_STRIDE];
      for (;;) {
        int s = aldi(my);
        if (__all(s >= t)) break;
        __builtin_amdgcn_s_sleep(4);    // long window: scan is ~2-4 us
      }
    }
    __syncthreads();
    asm volatile("" ::: "memory");

    // ---- h-part GEMM: one-shot bulk h loads, B = LDS W frags ----
    {
      U16 af[16];
#pragma unroll
      for (int kt = 0; kt < 16; ++kt) {
        const u64* p = h_cl + (((size_t)ar * DH + kt * 32 + kx) >> 2);
        af[kt].q[0] = ald64(p);
        af[kt].q[1] = ald64(p + 1);
      }
#pragma unroll
      for (int kt = 0; kt < 16; kt += 2) {
        accE = __builtin_amdgcn_mfma_f32_16x16x32_bf16(af[kt].s,     WFRAG(16 + kt),     accE, 0, 0, 0);
        accO = __builtin_amdgcn_mfma_f32_16x16x32_bf16(af[kt + 1].s, WFRAG(16 + kt + 1), accO, 0, 0, 0);
      }
    }
    // ---- v publish (per-wave arrive: own drain, own sentinel) ----
    {
      const int rbase = (lane >> 4) << 2;
      float* vp = v_cl + (size_t)rbase * NGATE + nb + ar;
#pragma unroll
      for (int r = 0; r < 4; ++r)
        ast32((uint*)&vp[(size_t)r * NGATE], __float_as_uint(accE[r] + accO[r]));
      waitvm();
      if (lane == 0) asti(arrA, ep);
    }

    if (mem < ROWS_CL) {
      // ---- wait all 128 producer-wave sentinels (short window) ----
      if (wave == 0) {
        const int* my0 = &slotA[lane * SLOT_STRIDE];
        const int* my1 = &slotA[(lane + 64) * SLOT_STRIDE];
        for (;;) {
          int s0 = aldi(my0);
          int s1 = aldi(my1);
          if (__all(s0 >= ep && s1 >= ep)) break;
          __builtin_amdgcn_s_sleep(1);
        }
      }
      __syncthreads();
      asm volatile("" ::: "memory");
      // ---- scan row `mem`: wave = gate ----
      {
        const int g  = wave;
        const int e0 = lane << 3;
        const u64* vr = (const u64*)(v_cl + (size_t)mem * NGATE + g * DH + e0);
        UF2 w0, w1, w2, w3;
        w0.q = ald64(vr);     w1.q = ald64(vr + 1);
        w2.q = ald64(vr + 2); w3.q = ald64(vr + 3);
        float p0 = __cosf(w0.f[0] + btr[0]);
        float p1 = __cosf(w0.f[1] + btr[1]);
        float p2 = __cosf(w1.f[0] + btr[2]);
        float p3 = __cosf(w1.f[1] + btr[3]);
        float p4 = __cosf(w2.f[0] + btr[4]);
        float p5 = __cosf(w2.f[1] + btr[5]);
        float p6 = __cosf(w3.f[0] + btr[6]);
        float p7 = __cosf(w3.f[1] + btr[7]);
        float q0 = p0, q1 = q0 * p1, q2 = q1 * p2, q3 = q2 * p3;
        float q4 = q3 * p4, q5 = q4 * p5, q6 = q5 * p6, q7 = q6 * p7;
        float a = q7;
#pragma unroll
        for (int off = 1; off < 64; off <<= 1) {
          float o = __shfl_up(a, off);
          a = (lane >= off) ? a * o : a;
        }
        float ex = __shfl_up(a, 1);
        ex = (lane == 0) ? 1.f : ex;
        float G0 = ex * q0, G1 = ex * q1, G2 = ex * q2, G3 = ex * q3;
        float G4 = ex * q4, G5 = ex * q5, G6 = ex * q6, G7 = ex * q7;
        float4 r0, r1;
        if (g == 2) {
          r0 = make_float4(tanhf_(G0), tanhf_(G1), tanhf_(G2), tanhf_(G3));
          r1 = make_float4(tanhf_(G4), tanhf_(G5), tanhf_(G6), tanhf_(G7));
        } else {
          r0 = make_float4(sigm(G0), sigm(G1), sigm(G2), sigm(G3));
          r1 = make_float4(sigm(G4), sigm(G5), sigm(G6), sigm(G7));
        }
        *(float4*)&lds_g[g * DH + e0]     = r0;
        *(float4*)&lds_g[g * DH + e0 + 4] = r1;
      }
      __syncthreads();   // all 4 gate slices in lds_g
      {
        const int k = tid << 1;
        float f0 = lds_g[0 * DH + k], f1 = lds_g[0 * DH + k + 1];
        float i0 = lds_g[1 * DH + k], i1 = lds_g[1 * DH + k + 1];
        float u0 = lds_g[2 * DH + k], u1 = lds_g[2 * DH + k + 1];
        float o0 = lds_g[3 * DH + k], o1 = lds_g[3 * DH + k + 1];
        c0 = f0 * c0 + i0 * u0;
        c1 = f1 * c1 + i1 * u1;
        float h0 = o0 * tanhf_(c0);
        float h1 = o1 * tanhf_(c1);
        // h words FIRST (critical path), then sentinel, then out[] stores
        uint hbits = ((uint)f2bf(h1) << 16) | (uint)f2bf(h0);
        ast32(&h_cl32[mem * 256 + tid], hbits);
        waitvm();                       // drains this wave's h stores
        if (lane == 0) asti(arrB, ep);
        float2 hp = make_float2(h0, h1);
        *(float2*)&out[((size_t)t * BATCH + row) * DH + k] = hp;
        if (t == T_STEPS - 1) {
          *(float2*)&out[OUT_HX + (size_t)row * DH + k] = hp;
          float2 cp = make_float2(c0, c1);
          *(float2*)&out[OUT_CX + (size_t)row * DH + k] = cp;
        }
      }
      __syncthreads();   // lds_g WAR protection (R6-proven)
    }

    // ---- overlapped x-part of t+1 (placement as R6) ----
    if (t + 1 < T_STEPS) XPART(t + 1);
  }
#undef XPART
#undef WFRAG
}

extern "C" void kernel_launch(void* const* d_in, const int* in_sizes, int n_in,
                              void* d_out, int out_size, void* d_ws, size_t ws_size,
                              hipStream_t stream) {
  const float* X  = (const float*)d_in[0];
  const float* Wf = (const float*)d_in[1];
  const float* bf = (const float*)d_in[2];
  const float* tf = (const float*)d_in[3];
  const float* Wi = (const float*)d_in[4];
  const float* bi = (const float*)d_in[5];
  const float* ti = (const float*)d_in[6];
  const float* Wu = (const float*)d_in[7];
  const float* bu = (const float*)d_in[8];
  const float* tu = (const float*)d_in[9];
  const float* Wo = (const float*)d_in[10];
  const float* bo = (const float*)d_in[11];
  const float* to = (const float*)d_in[12];

  char* ws = (char*)d_ws;
  ushort* Wb     = (ushort*)(ws + WB_OFF);
  ushort* Xb     = (ushort*)(ws + XB_OFF);
  float*  bt     = (float*)(ws + BT_OFF);
  char*   clbase = ws + CL_OFF;
  float*  out    = (float*)d_out;

  static bool attr_set = false;
  if (!attr_set) {
    hipFuncSetAttribute((const void*)qlstm_main,
                        hipFuncAttributeMaxDynamicSharedMemorySize, LDS_TOTAL);
    attr_set = true;
  }

  k_prep_w<<<dim3((NGATE * 1024 / 4 + 255) / 256), dim3(256), 0, stream>>>(Wf, Wi, Wu, Wo, Wb);
  k_prep_x<<<dim3((T_STEPS * BATCH * DIN / 4 + 255) / 256), dim3(256), 0, stream>>>(X, Xb);
  k_prep_misc<<<dim3(256), dim3(256), 0, stream>>>(bf, tf, bi, ti, bu, tu, bo, to, bt, clbase);
  qlstm_main<<<dim3(NWG), dim3(256), LDS_TOTAL, stream>>>(Xb, Wb, bt, clbase, out);
}

// Round 10
// 1627.822 us; speedup vs baseline: 2.0912x; 1.4045x over previous
//
#include <hip/hip_runtime.h>
#include <hip/hip_bf16.h>

// R10: XCD-local DATA plane + agent CONTROL plane.
//  - Flags: R6-proven relaxed agent atomics (identical poll loops -> cannot
//    introduce a new hang class).
//  - Data (v, h): plain write-through stores (ack'd in the XCD L2 by the
//    __syncthreads vmcnt drain) + plain loads after ONE buffer_inv (vector L1
//    invalidate) per hop, issued only after the flag is observed. Same-XCD L2
//    is the coherence domain -> no MALL round-trips, no write-through to HBM.
//  - Placement verified at runtime: s_getreg(HW_REG_XCC_ID) census (m09);
//    every XCD must hold exactly 32 WGs, else fall back to the byte-identical
//    R6 agent transport. Both modes compute identical arithmetic.
//  - Failure modes are visible: buffer_inv wrong => absmax error (not hang);
//    placement odd => fallback (R6 perf).
#define T_STEPS 256
#define BATCH   128
#define DIN     512
#define DH      512
#define NGATE   2048
#define NCL     8
#define WPC     32
#define ROWS_CL 16
#define NWG     (NCL * WPC)

typedef __attribute__((ext_vector_type(8))) short short8;
typedef __attribute__((ext_vector_type(4))) float f32x4;
typedef unsigned long long u64;

#define OUT_HX ((size_t)T_STEPS * BATCH * DH)
#define OUT_CX (OUT_HX + (size_t)BATCH * DH)

// ---- ws layout (R6 + boot table) ----
#define WB_OFF    0
#define XB_OFF    (4 * 1024 * 1024)
#define BT_OFF    (XB_OFF + 32 * 1024 * 1024)
#define CL_OFF    (BT_OFF + 8192)
#define CL_STRIDE (160 * 1024)
#define CLV_OFF   0                  // v: 16*2048*4 = 131072 B
#define CLH_OFF   131072             // h: 16*512*2  =  16384 B
#define CLF_OFF   147456             // slotA: 32 x 128 B = 4096 B
#define CLFB_OFF  (CLF_OFF + 4096)   // slotB: 16 x 128 B = 2048 B
#define SLOT_STRIDE 32               // ints per slot (128 B)
#define BOOT_OFF  (CL_OFF + NCL * CL_STRIDE)

#define LDS_W_BYTES 131072           // 64 cols x 1024 K x bf16, swizzled
#define LDS_TOTAL   (LDS_W_BYTES + 4 * DH * 4)

__device__ inline ushort f2bf(float x) {
  uint u = __float_as_uint(x);
  u += 0x7fffu + ((u >> 16) & 1u);
  return (ushort)(u >> 16);
}
__device__ inline float sigm(float x) { return 1.f / (1.f + __expf(-x)); }
__device__ inline float tanhf_(float x) { return 1.f - 2.f / (1.f + __expf(2.f * x)); }

// agent-scope (coherence-point) ops — R6-proven
__device__ inline u64 ald64(const u64* p) {
  return __hip_atomic_load(p, __ATOMIC_RELAXED, __HIP_MEMORY_SCOPE_AGENT);
}
__device__ inline void ast32(uint* p, uint v) {
  __hip_atomic_store(p, v, __ATOMIC_RELAXED, __HIP_MEMORY_SCOPE_AGENT);
}
__device__ inline int aldi(const int* p) {
  return __hip_atomic_load(p, __ATOMIC_RELAXED, __HIP_MEMORY_SCOPE_AGENT);
}
__device__ inline void asti(int* p, int v) {
  __hip_atomic_store(p, v, __ATOMIC_RELAXED, __HIP_MEMORY_SCOPE_AGENT);
}
// L1 invalidate (LOCAL mode): next plain loads refill from XCD L2
__device__ inline void l1inv() {
  asm volatile("buffer_inv" ::: "memory");
  asm volatile("s_waitcnt vmcnt(0)" ::: "memory");
}

union U16 { u64 q[2]; short8 s; };
union UF2 { u64 q; float f[2]; };

// -------- prep kernels --------
__global__ void k_prep_w(const float* __restrict__ Wf, const float* __restrict__ Wi,
                         const float* __restrict__ Wu, const float* __restrict__ Wo,
                         ushort* __restrict__ Wb) {
  size_t i4 = ((size_t)blockIdx.x * 256 + threadIdx.x) * 4;
  if (i4 >= (size_t)NGATE * 1024) return;
  int row = (int)(i4 >> 10);
  int col = (int)(i4 & 1023);
  const float* W = (row < 512) ? Wf : (row < 1024) ? Wi : (row < 1536) ? Wu : Wo;
  int r = row & 511;
  float4 w = *(const float4*)&W[(size_t)r * 1024 + col];
  ushort4 o = make_ushort4(f2bf(w.x), f2bf(w.y), f2bf(w.z), f2bf(w.w));
  *(ushort4*)&Wb[i4] = o;
}

__global__ void k_prep_x(const float* __restrict__ X, ushort* __restrict__ Xb) {
  size_t i4 = ((size_t)blockIdx.x * 256 + threadIdx.x) * 4;
  if (i4 >= (size_t)T_STEPS * BATCH * DIN) return;
  float4 xv = *(const float4*)&X[i4];
  ushort4 o = make_ushort4(f2bf(xv.x), f2bf(xv.y), f2bf(xv.z), f2bf(xv.w));
  *(ushort4*)&Xb[i4] = o;
}

__global__ void k_prep_misc(const float* __restrict__ bf_, const float* __restrict__ tf_,
                            const float* __restrict__ bi_, const float* __restrict__ ti_,
                            const float* __restrict__ bu_, const float* __restrict__ tu_,
                            const float* __restrict__ bo_, const float* __restrict__ to_,
                            float* __restrict__ bt, char* __restrict__ clbase,
                            int* __restrict__ boot) {
  int idx = blockIdx.x * 256 + threadIdx.x;
  if (idx < NGATE) {
    int g = idx >> 9, k = idx & 511;
    const float* b = (g == 0) ? bf_ : (g == 1) ? bi_ : (g == 2) ? bu_ : bo_;
    const float* t = (g == 0) ? tf_ : (g == 1) ? ti_ : (g == 2) ? tu_ : to_;
    bt[idx] = b[k] + t[k];
  }
  if (idx < NCL * 4096) {  // zero h (16*512 bf16 = 4096 uints per cluster)
    int c = idx >> 12, w = idx & 4095;
    ((uint*)(clbase + (size_t)c * CL_STRIDE + CLH_OFF))[w] = 0u;
  }
  if (idx < NCL * 2048) {  // zero flag region (8 KB per cluster)
    int c = idx >> 11, w = idx & 2047;
    ((int*)(clbase + (size_t)c * CL_STRIDE + CLF_OFF))[w] = 0;
  }
  if (idx < 16) boot[idx] = 0;
}

// -------- main loop body (transport-templated: L = XCD-local data) --------
template<bool L>
__device__ __forceinline__ void run_main(
    const ushort* __restrict__ Xb, const ushort* __restrict__ Wb,
    const float* __restrict__ bt, char* cl, float* __restrict__ out,
    int cluster, int mem, ushort* wlds, float* lds_g) {
  const int tid  = threadIdx.x;
  const int lane = tid & 63;
  const int wave = tid >> 6;

  float*  v_cl  = (float*)(cl + CLV_OFF);
  u64*    h_cl  = (u64*)(cl + CLH_OFF);
  uint*   h_cl32= (uint*)(cl + CLH_OFF);
  int*    slotA = (int*)(cl + CLF_OFF);
  int*    slotB = (int*)(cl + CLFB_OFF);

  const int nb    = mem * 64 + wave * 16;
  const int ar    = lane & 15;
  const int kx    = (lane >> 4) << 3;      // ushort units
  const int crow0 = cluster * ROWS_CL;
  const int row   = crow0 + mem;
  const int wrow  = wave * 16 + ar;

  // ---- stage W slice into LDS (XOR-swizzled rows) ----
  {
    const char* wsrc = (const char*)(Wb + (size_t)(mem * 64) * 1024);
#pragma unroll
    for (int it = 0; it < 32; ++it) {
      int idx16 = it * 256 + tid;
      int r  = idx16 >> 7;
      int kb = (idx16 & 127) << 4;
      short8 w = *(const short8*)(wsrc + (size_t)r * 2048 + kb);
      *(short8*)((char*)wlds + (size_t)r * 2048 + (kb ^ ((r & 7) << 4))) = w;
    }
  }
#define WFRAG(KT) (*(const short8*)((const char*)wlds + (size_t)wrow * 2048 + \
                    ((((KT) * 64) + (kx << 1)) ^ ((ar & 7) << 4))))

  float btr[8];
  {
    const int e0 = lane << 3;
#pragma unroll
    for (int j = 0; j < 8; ++j) btr[j] = bt[wave * DH + e0 + j];
  }
  __syncthreads();

  float c0 = 0.f, c1 = 0.f;
  f32x4 accE = {0.f, 0.f, 0.f, 0.f}, accO = {0.f, 0.f, 0.f, 0.f};

#define XPART(TT) do {                                                        \
    accE = (f32x4){0.f, 0.f, 0.f, 0.f};                                       \
    accO = (f32x4){0.f, 0.f, 0.f, 0.f};                                       \
    const ushort* Ax = Xb + ((size_t)(TT) * BATCH + crow0 + ar) * DIN + kx;   \
    _Pragma("unroll")                                                         \
    for (int kt = 0; kt < 16; kt += 2) {                                      \
      short8 a0 = *(const short8*)(Ax + kt * 32);                             \
      short8 a1 = *(const short8*)(Ax + (kt + 1) * 32);                       \
      accE = __builtin_amdgcn_mfma_f32_16x16x32_bf16(a0, WFRAG(kt), accE, 0, 0, 0);     \
      accO = __builtin_amdgcn_mfma_f32_16x16x32_bf16(a1, WFRAG(kt + 1), accO, 0, 0, 0); \
    }                                                                         \
  } while (0)

  XPART(0);

  for (int t = 0; t < T_STEPS; ++t) {
    const int ep = t + 1;
    // ---- h-part GEMM: A = h (L: plain/L2 after inv; else agent) ----
    {
      U16 af[16];
#pragma unroll
      for (int kt = 0; kt < 16; ++kt) {
        const u64* p = h_cl + (((size_t)ar * DH + kt * 32 + kx) >> 2);
        if constexpr (L) { af[kt].q[0] = p[0];       af[kt].q[1] = p[1]; }
        else             { af[kt].q[0] = ald64(p);   af[kt].q[1] = ald64(p + 1); }
      }
#pragma unroll
      for (int kt = 0; kt < 16; kt += 2) {
        accE = __builtin_amdgcn_mfma_f32_16x16x32_bf16(af[kt].s,     WFRAG(16 + kt),     accE, 0, 0, 0);
        accO = __builtin_amdgcn_mfma_f32_16x16x32_bf16(af[kt + 1].s, WFRAG(16 + kt + 1), accO, 0, 0, 0);
      }
    }
    // ---- v slice publish ----
    {
      const int rbase = (lane >> 4) << 2;
      float* vp = v_cl + (size_t)rbase * NGATE + nb + ar;
#pragma unroll
      for (int r = 0; r < 4; ++r) {
        float val = accE[r] + accO[r];
        if constexpr (L) vp[(size_t)r * NGATE] = val;
        else             ast32((uint*)&vp[(size_t)r * NGATE], __float_as_uint(val));
      }
    }
    __syncthreads();   // per-wave vmcnt drain: stores ack'd (L: XCD L2)
    if (tid == 0) asti(&slotA[mem * SLOT_STRIDE], ep);

    if (mem < ROWS_CL) {
      // ---- wait all 32 v slices (agent flags, R6-narrow poll) ----
      if (wave == 0) {
        for (;;) {
          int s = (lane < WPC) ? aldi(&slotA[lane * SLOT_STRIDE]) : ep;
          if (__all(s >= ep)) break;
          __builtin_amdgcn_s_sleep(1);
        }
        if constexpr (L) l1inv();   // refill data lines from XCD L2
      }
      __syncthreads();
      asm volatile("" ::: "memory");
      // ---- scan row `mem`: wave = gate ----
      {
        const int g  = wave;
        const int e0 = lane << 3;
        const u64* vr = (const u64*)(v_cl + (size_t)mem * NGATE + g * DH + e0);
        UF2 w0, w1, w2, w3;
        if constexpr (L) { w0.q = vr[0]; w1.q = vr[1]; w2.q = vr[2]; w3.q = vr[3]; }
        else { w0.q = ald64(vr); w1.q = ald64(vr + 1); w2.q = ald64(vr + 2); w3.q = ald64(vr + 3); }
        float p0 = __cosf(w0.f[0] + btr[0]);
        float p1 = __cosf(w0.f[1] + btr[1]);
        float p2 = __cosf(w1.f[0] + btr[2]);
        float p3 = __cosf(w1.f[1] + btr[3]);
        float p4 = __cosf(w2.f[0] + btr[4]);
        float p5 = __cosf(w2.f[1] + btr[5]);
        float p6 = __cosf(w3.f[0] + btr[6]);
        float p7 = __cosf(w3.f[1] + btr[7]);
        float q0 = p0, q1 = q0 * p1, q2 = q1 * p2, q3 = q2 * p3;
        float q4 = q3 * p4, q5 = q4 * p5, q6 = q5 * p6, q7 = q6 * p7;
        float a = q7;
#pragma unroll
        for (int off = 1; off < 64; off <<= 1) {
          float o = __shfl_up(a, off);
          a = (lane >= off) ? a * o : a;
        }
        float ex = __shfl_up(a, 1);
        ex = (lane == 0) ? 1.f : ex;
        float G0 = ex * q0, G1 = ex * q1, G2 = ex * q2, G3 = ex * q3;
        float G4 = ex * q4, G5 = ex * q5, G6 = ex * q6, G7 = ex * q7;
        float4 r0, r1;
        if (g == 2) {
          r0 = make_float4(tanhf_(G0), tanhf_(G1), tanhf_(G2), tanhf_(G3));
          r1 = make_float4(tanhf_(G4), tanhf_(G5), tanhf_(G6), tanhf_(G7));
        } else {
          r0 = make_float4(sigm(G0), sigm(G1), sigm(G2), sigm(G3));
          r1 = make_float4(sigm(G4), sigm(G5), sigm(G6), sigm(G7));
        }
        *(float4*)&lds_g[g * DH + e0]     = r0;
        *(float4*)&lds_g[g * DH + e0 + 4] = r1;
      }
      __syncthreads();
      {
        const int k = tid << 1;
        float f0 = lds_g[0 * DH + k], f1 = lds_g[0 * DH + k + 1];
        float i0 = lds_g[1 * DH + k], i1 = lds_g[1 * DH + k + 1];
        float u0 = lds_g[2 * DH + k], u1 = lds_g[2 * DH + k + 1];
        float o0 = lds_g[3 * DH + k], o1 = lds_g[3 * DH + k + 1];
        c0 = f0 * c0 + i0 * u0;
        c1 = f1 * c1 + i1 * u1;
        float h0 = o0 * tanhf_(c0);
        float h1 = o1 * tanhf_(c1);
        float2 hp = make_float2(h0, h1);
        *(float2*)&out[((size_t)t * BATCH + row) * DH + k] = hp;
        uint hbits = ((uint)f2bf(h1) << 16) | (uint)f2bf(h0);
        if constexpr (L) h_cl32[mem * 256 + tid] = hbits;
        else             ast32(&h_cl32[mem * 256 + tid], hbits);
        if (t == T_STEPS - 1) {
          *(float2*)&out[OUT_HX + (size_t)row * DH + k] = hp;
          float2 cp = make_float2(c0, c1);
          *(float2*)&out[OUT_CX + (size_t)row * DH + k] = cp;
        }
      }
      __syncthreads();   // drain h stores (L: L2-ack) + lds_g WAR
      if (tid == 0) asti(&slotB[mem * SLOT_STRIDE], ep);
    }

    if (t + 1 < T_STEPS) {
      // ---- overlapped x-part of t+1 (needs no h) ----
      XPART(t + 1);
      // ---- wait all 16 h rows (agent flags) ----
      if (wave == 0) {
        for (;;) {
          int s = (lane < ROWS_CL) ? aldi(&slotB[lane * SLOT_STRIDE]) : ep;
          if (__all(s >= ep)) break;
          __builtin_amdgcn_s_sleep(1);
        }
        if constexpr (L) l1inv();   // refill h lines from XCD L2
      }
      __syncthreads();
      asm volatile("" ::: "memory");
    }
  }
#undef XPART
#undef WFRAG
}

// -------- persistent main kernel --------
__global__ __launch_bounds__(256, 1) void qlstm_main(
    const ushort* __restrict__ Xb, const ushort* __restrict__ Wb,
    const float* __restrict__ bt, char* __restrict__ clbase,
    int* __restrict__ boot, float* __restrict__ out) {
  extern __shared__ char smem[];
  ushort* wlds  = (ushort*)smem;
  float*  lds_g = (float*)(smem + LDS_W_BYTES);

  __shared__ int shboot[4];
  const int tid = threadIdx.x;

  // ---- bootstrap: XCD census via proven agent atomics (one-time) ----
  if (tid == 0) {
    uint xcc;
    asm volatile("s_getreg_b32 %0, hwreg(HW_REG_XCC_ID)" : "=s"(xcc));
    xcc &= 7;
    int slot = __hip_atomic_fetch_add(&boot[xcc], 1, __ATOMIC_RELAXED, __HIP_MEMORY_SCOPE_AGENT);
    __hip_atomic_fetch_add(&boot[8], 1, __ATOMIC_RELAXED, __HIP_MEMORY_SCOPE_AGENT);
    while (__hip_atomic_load(&boot[8], __ATOMIC_RELAXED, __HIP_MEMORY_SCOPE_AGENT) < NWG)
      __builtin_amdgcn_s_sleep(8);
    int ok = 1;
#pragma unroll
    for (int c2 = 0; c2 < NCL; ++c2)
      ok &= (__hip_atomic_load(&boot[c2], __ATOMIC_RELAXED, __HIP_MEMORY_SCOPE_AGENT) == WPC);
    shboot[0] = (int)xcc;
    shboot[1] = slot;
    shboot[2] = ok;
  }
  __syncthreads();
  const int local_ok = shboot[2];
  const int cluster  = local_ok ? shboot[0] : ((int)blockIdx.x & 7);
  const int mem      = local_ok ? shboot[1] : ((int)blockIdx.x >> 3);
  char* cl = clbase + (size_t)cluster * CL_STRIDE;

  if (local_ok)
    run_main<true>(Xb, Wb, bt, cl, out, cluster, mem, wlds, lds_g);
  else
    run_main<false>(Xb, Wb, bt, cl, out, cluster, mem, wlds, lds_g);
}

extern "C" void kernel_launch(void* const* d_in, const int* in_sizes, int n_in,
                              void* d_out, int out_size, void* d_ws, size_t ws_size,
                              hipStream_t stream) {
  const float* X  = (const float*)d_in[0];
  const float* Wf = (const float*)d_in[1];
  const float* bf = (const float*)d_in[2];
  const float* tf = (const float*)d_in[3];
  const float* Wi = (const float*)d_in[4];
  const float* bi = (const float*)d_in[5];
  const float* ti = (const float*)d_in[6];
  const float* Wu = (const float*)d_in[7];
  const float* bu = (const float*)d_in[8];
  const float* tu = (const float*)d_in[9];
  const float* Wo = (const float*)d_in[10];
  const float* bo = (const float*)d_in[11];
  const float* to = (const float*)d_in[12];

  char* ws = (char*)d_ws;
  ushort* Wb     = (ushort*)(ws + WB_OFF);
  ushort* Xb     = (ushort*)(ws + XB_OFF);
  float*  bt     = (float*)(ws + BT_OFF);
  char*   clbase = ws + CL_OFF;
  int*    boot   = (int*)(ws + BOOT_OFF);
  float*  out    = (float*)d_out;

  static bool attr_set = false;
  if (!attr_set) {
    hipFuncSetAttribute((const void*)qlstm_main,
                        hipFuncAttributeMaxDynamicSharedMemorySize, LDS_TOTAL);
    attr_set = true;
  }

  k_prep_w<<<dim3((NGATE * 1024 / 4 + 255) / 256), dim3(256), 0, stream>>>(Wf, Wi, Wu, Wo, Wb);
  k_prep_x<<<dim3((T_STEPS * BATCH * DIN / 4 + 255) / 256), dim3(256), 0, stream>>>(X, Xb);
  k_prep_misc<<<dim3(256), dim3(256), 0, stream>>>(bf, tf, bi, ti, bu, tu, bo, to, bt, clbase, boot);
  qlstm_main<<<dim3(NWG), dim3(256), LDS_TOTAL, stream>>>(Xb, Wb, bt, clbase, boot, out);
}